// Round 2
// baseline (71.571 us; speedup 1.0000x reference)
//
#include <hip/hip_runtime.h>

#define I_FEAT 8192
#define O_FEAT 8192
#define BATCH  1024

using f4 = __attribute__((ext_vector_type(4))) float;

// ---------------- K1: partial column sums of W ----------------
// Grid: NS row-splits x 8 col-blocks (1024 cols each). 256 thr x float4.
// 8 independent row-streams in flight per iteration for HBM latency hiding.
template <int NS>
__global__ __launch_bounds__(256) void colsum_partial_kernel(
    const float* __restrict__ W, float* __restrict__ partials) {
  constexpr int RPS = O_FEAT / NS;  // rows per split
  const int cb    = blockIdx.x & 7;
  const int split = blockIdx.x >> 3;
  const int c     = (cb << 10) | (threadIdx.x << 2);
  const float* base = W + (size_t)split * RPS * I_FEAT + c;

  f4 acc[8];
#pragma unroll
  for (int u = 0; u < 8; ++u) acc[u] = (f4)(0.f);

  for (int r = 0; r < RPS; r += 8) {
#pragma unroll
    for (int u = 0; u < 8; ++u) {
      f4 v = __builtin_nontemporal_load(
          (const f4*)(base + (size_t)(r + u) * I_FEAT));
      acc[u] += v;
    }
  }
  f4 s = ((acc[0] + acc[1]) + (acc[2] + acc[3])) +
         ((acc[4] + acc[5]) + (acc[6] + acc[7]));
  *(f4*)(partials + (size_t)split * I_FEAT + c) = s;
}

// ---------------- K2: partials -> colsum; block 8 reduces b -> bsum --------
template <int NS>
__global__ __launch_bounds__(256) void finalize_colsum_kernel(
    const float* __restrict__ partials, const float* __restrict__ b,
    float* __restrict__ colsum, float* __restrict__ bsum) {
  __shared__ float red[4];
  if (blockIdx.x < 8) {
    const int c = (blockIdx.x << 10) | (threadIdx.x << 2);
    f4 s = (f4)(0.f);
#pragma unroll 4
    for (int sp = 0; sp < NS; ++sp)
      s += __builtin_nontemporal_load(
          (const f4*)(partials + (size_t)sp * I_FEAT + c));
    *(f4*)(colsum + c) = s;
  } else {
    float s = 0.f;
    const f4* b4 = (const f4*)b;
    for (int j = threadIdx.x; j < I_FEAT / 4; j += 256) {
      f4 v = __builtin_nontemporal_load(b4 + j);
      s += (v.x + v.y) + (v.z + v.w);
    }
#pragma unroll
    for (int off = 32; off; off >>= 1) s += __shfl_down(s, off);
    if ((threadIdx.x & 63) == 0) red[threadIdx.x >> 6] = s;
    __syncthreads();
    if (threadIdx.x == 0) bsum[0] = (red[0] + red[1]) + (red[2] + red[3]);
  }
}

// ---------------- K3: out[row] = dot(x[row], colsum) + bsum ----------------
__global__ __launch_bounds__(256) void rowdot_kernel(
    const float* __restrict__ x, const float* __restrict__ colsum,
    const float* __restrict__ bsum, float* __restrict__ out) {
  __shared__ float red[4];
  const int row = blockIdx.x;
  const f4* xr = (const f4*)(x + (size_t)row * I_FEAT);
  const f4* cs = (const f4*)colsum;

  float s = 0.f;
#pragma unroll
  for (int j = 0; j < 8; ++j) {  // 8 * 256 * 4 = 8192 cols
    const int idx = threadIdx.x + j * 256;
    f4 a = __builtin_nontemporal_load(xr + idx);
    f4 c = cs[idx];
    s += a.x * c.x + a.y * c.y + a.z * c.z + a.w * c.w;
  }
#pragma unroll
  for (int off = 32; off; off >>= 1) s += __shfl_down(s, off);
  if ((threadIdx.x & 63) == 0) red[threadIdx.x >> 6] = s;
  __syncthreads();
  if (threadIdx.x == 0)
    out[row] = (red[0] + red[1]) + (red[2] + red[3]) + bsum[0];
}

extern "C" void kernel_launch(void* const* d_in, const int* in_sizes, int n_in,
                              void* d_out, int out_size, void* d_ws, size_t ws_size,
                              hipStream_t stream) {
  const float* x = (const float*)d_in[0];  // (1024, 8192)
  const float* W = (const float*)d_in[1];  // (8192, 8192)
  const float* b = (const float*)d_in[2];  // (8192,)
  float* out = (float*)d_out;              // (1024,)

  // ws layout: partials [NS][8192] f32 | colsum [8192] f32 | bsum [1] f32
  float* partials = (float*)d_ws;

  const size_t need128 = (size_t)128 * I_FEAT * 4 + (size_t)I_FEAT * 4 + 16;
  if (ws_size >= need128) {
    constexpr int NS = 128;
    float* colsum = partials + (size_t)NS * I_FEAT;
    float* bsum   = colsum + I_FEAT;
    colsum_partial_kernel<NS><<<NS * 8, 256, 0, stream>>>(W, partials);
    finalize_colsum_kernel<NS><<<9, 256, 0, stream>>>(partials, b, colsum, bsum);
    rowdot_kernel<<<BATCH, 256, 0, stream>>>(x, colsum, bsum, out);
  } else {
    constexpr int NS = 64;
    float* colsum = partials + (size_t)NS * I_FEAT;
    float* bsum   = colsum + I_FEAT;
    colsum_partial_kernel<NS><<<NS * 8, 256, 0, stream>>>(W, partials);
    finalize_colsum_kernel<NS><<<9, 256, 0, stream>>>(partials, b, colsum, bsum);
    rowdot_kernel<<<BATCH, 256, 0, stream>>>(x, colsum, bsum, out);
  }
}